// Round 5
// baseline (151.478 us; speedup 1.0000x reference)
//
#include <hip/hip_runtime.h>
#include <stdint.h>
#include <math.h>

#define BNTH 256           // nms/collect block size (4 waves)
#define CAP 1024           // max candidates per class-task
#define MAXK 50
#define THRESH_F 0.05f
#define NMS_T 0.3f

// Decode one (image b, row n, class c) box exactly like the reference:
// bbox_transform_inv + clip + /scale.  (Arithmetic identical to the version
// that passed with absmax 0.0 -- do not reorder.)
__device__ __forceinline__ void decode_box(
    const float* __restrict__ rois, const float* __restrict__ pred,
    float H, float W, float scale,
    int b, int n, int c, int N, int C, float out[4])
{
    const float* r = rois + ((size_t)b * N + n) * 5;
    float bx1 = r[1], by1 = r[2], bx2 = r[3], by2 = r[4];
    float w  = bx2 - bx1 + 1.0f;
    float h  = by2 - by1 + 1.0f;
    float cx = bx1 + 0.5f * w;
    float cy = by1 + 0.5f * h;
    const float* d = pred + ((size_t)b * N + n) * 4 * C + 4 * c;
    float dx = d[0] * 0.1f, dy = d[1] * 0.1f;
    float dw = d[2] * 0.2f, dh = d[3] * 0.2f;
    float pcx = dx * w + cx;
    float pcy = dy * h + cy;
    float pw  = expf(dw) * w;
    float ph  = expf(dh) * h;
    float X1 = fminf(fmaxf(pcx - 0.5f * pw, 0.0f), W - 1.0f);
    float Y1 = fminf(fmaxf(pcy - 0.5f * ph, 0.0f), H - 1.0f);
    float X2 = fminf(fmaxf(pcx + 0.5f * pw, 0.0f), W - 1.0f);
    float Y2 = fminf(fmaxf(pcy + 0.5f * ph, 0.0f), H - 1.0f);
    out[0] = X1 / scale;
    out[1] = Y1 / scale;
    out[2] = X2 / scale;
    out[3] = Y2 / scale;
}

// Kernel A: fully-coalesced threshold scan over all scores.  One thread per
// (stream,image,row,class) score element -> atomic append key into the
// per-(stream,image,class) candidate list.  Append order is nondeterministic
// but keys are unique (row in low bits); the sort in kernel B canonicalizes.
__global__ __launch_bounds__(BNTH) void collect_kernel(
    const float* __restrict__ cls_A, const float* __restrict__ cls_B,
    int Bimg, int N, int C,
    int* __restrict__ cnt, unsigned long long* __restrict__ keys_ws)
{
    const int FG = C - 1;
    const size_t total = (size_t)2 * Bimg * N * C;
    const size_t idx = (size_t)blockIdx.x * BNTH + threadIdx.x;
    if (idx >= total) return;
    const int c = (int)(idx % C);
    const size_t t = idx / C;
    const int n = (int)(t % N);
    const int ib = (int)(t / N);              // global image 0..2*Bimg-1
    const int st = ib >= Bimg;
    const int b  = ib - st * Bimg;
    const float* cls = st ? cls_B : cls_A;
    const float sc = cls[((size_t)b * N + n) * C + c];
    if (c > 0 && sc > THRESH_F) {
        const int task = ib * FG + (c - 1);
        const int slot = atomicAdd(&cnt[task], 1);
        if (slot < CAP)
            keys_ws[(size_t)task * CAP + slot] =
                ((uint64_t)__float_as_uint(sc) << 32) | (uint32_t)(~(uint32_t)n);
    }
}

// Register bitonic sort, descending, over SN elements laid out as
// index i = s*64 + lane (slot-major), on ONE wave.  Keys are u64
// (score<<32|~row) reinterpreted as POSITIVE doubles (exponent field normal,
// never NaN), so f64 fmax/fmin ordering == u64 ordering.
template<int SN>
__device__ __forceinline__ void bitonic_desc(double* kd, int lane)
{
    constexpr int NS = SN / 64;
    #pragma unroll
    for (int k = 2; k <= SN; k <<= 1) {
        #pragma unroll
        for (int j = k >> 1; j >= 1; j >>= 1) {
            if (j >= 64) {
                const int js = j >> 6;
                #pragma unroll
                for (int s = 0; s < NS; ++s) {
                    if ((s & js) == 0) {
                        const int sp = s | js;
                        const bool d = (((s << 6) & k) == 0);  // compile-time
                        const double a = kd[s], bb = kd[sp];
                        kd[s]  = d ? fmax(a, bb) : fmin(a, bb);
                        kd[sp] = d ? fmin(a, bb) : fmax(a, bb);
                    }
                }
            } else {
                #pragma unroll
                for (int s = 0; s < NS; ++s) {
                    const double o = __shfl_xor(kd[s], j);
                    const bool lower = (lane & j) == 0;
                    const bool d = ((((s << 6) | lane) & k) == 0);
                    const bool takeMax = (d == lower);
                    const double mx = fmax(kd[s], o);
                    const double mn = fmin(kd[s], o);
                    kd[s] = takeMax ? mx : mn;
                }
            }
        }
    }
}

// Kernel B: one 4-wave block per (stream, image, fg-class).
// coalesced key load -> wave-0 register sort -> ALL-wave decode in sorted
// order (gathers get 4x TLP) -> wave-0 sorted-scan NMS.
__global__ __launch_bounds__(BNTH, 1) void nms_kernel(
    const float* __restrict__ rois_A, const float* __restrict__ pred_A,
    const float* __restrict__ info_A,
    const float* __restrict__ rois_B, const float* __restrict__ pred_B,
    const float* __restrict__ info_B,
    int Bimg, int N, int C,
    const int* __restrict__ cnt, const unsigned long long* __restrict__ keys_ws,
    float* __restrict__ kept_scores, int* __restrict__ kcounts,
    float* __restrict__ cls_box)
{
    const int FG = C - 1;
    const int bx = blockIdx.x;
    const int st  = bx / (Bimg * FG);
    const int rem = bx % (Bimg * FG);
    const int b = rem / FG;
    const int j = rem % FG;
    const int c = j + 1;
    const int tid = threadIdx.x;
    const int lane = tid & 63;

    const float* rois = st ? rois_B : rois_A;
    const float* pred = st ? pred_B : pred_A;
    const float* info = st ? info_B : info_A;

    __shared__ uint64_t keysL[CAP];
    __shared__ float4 boxL[CAP];
    __shared__ float  sarL[CAP];
    __shared__ float4 keptL[MAXK];

    const int rawM = cnt[bx];
    const int M = rawM < CAP ? rawM : CAP;

    // ---- Coalesced key load + zero padding ----
    for (int i = tid; i < CAP; i += BNTH)
        keysL[i] = (i < M) ? keys_ws[(size_t)bx * CAP + i] : 0ull;
    __syncthreads();

    // ---- Sort descending on wave 0 (registers; smallest sufficient net) ----
    if (tid < 64) {
        if (M > 1) {
            if (M <= 512) {
                double kd[8];
                #pragma unroll
                for (int s = 0; s < 8; ++s)
                    kd[s] = __longlong_as_double((long long)keysL[s * 64 + lane]);
                bitonic_desc<512>(kd, lane);
                #pragma unroll
                for (int s = 0; s < 8; ++s)
                    keysL[s * 64 + lane] = (uint64_t)__double_as_longlong(kd[s]);
            } else {
                double kd[16];
                #pragma unroll
                for (int s = 0; s < 16; ++s)
                    kd[s] = __longlong_as_double((long long)keysL[s * 64 + lane]);
                bitonic_desc<1024>(kd, lane);
                #pragma unroll
                for (int s = 0; s < 16; ++s)
                    keysL[s * 64 + lane] = (uint64_t)__double_as_longlong(kd[s]);
            }
        }
    }
    __syncthreads();

    // ---- Decode in SORTED order, all 4 waves (4x latency hiding) ----
    const float H = info[b * 3 + 0];
    const float W = info[b * 3 + 1];
    const float scale = info[b * 3 + 2];
    for (int i = tid; i < M; i += BNTH) {
        const uint64_t u = keysL[i];
        const int n = (int)(~(uint32_t)u);
        float o[4];
        decode_box(rois, pred, H, W, scale, b, n, c, N, C, o);
        boxL[i] = make_float4(o[0], o[1], o[2], o[3]);
        sarL[i] = (o[2] - o[0] + 1.0f) * (o[3] - o[1] + 1.0f);
    }
    __syncthreads();

    // ---- Scan NMS over sorted order on wave 0, 64 candidates per batch ----
    if (tid < 64) {
        const size_t obase = (size_t)bx;
        float* ksc = kept_scores + obase * MAXK;
        int kcount = 0;
        float4 cls_best = make_float4(0.f, 0.f, 0.f, 0.f);

        for (int s = 0; s * 64 < M && kcount < MAXK; ++s) {
            const int ii = s * 64 + lane;
            const bool valid = (ii < M);
            float cx1 = 0.f, cy1 = 0.f, cx2 = 0.f, cy2 = 0.f, car = 1.0f, csc = 0.f;
            if (valid) {
                const float4 cb4 = boxL[ii];
                cx1 = cb4.x; cy1 = cb4.y; cx2 = cb4.z; cy2 = cb4.w;
                car = sarL[ii];
                csc = __uint_as_float((uint32_t)(keysL[ii] >> 32));
            }
            // Pre-suppression vs already-kept boxes (uniform loop, pipelined).
            bool sup = !valid;
            for (int q = 0; q < kcount; ++q) {
                const float4 kb = keptL[q];
                const float kar = (kb.z - kb.x + 1.0f) * (kb.w - kb.y + 1.0f);
                const float ix1 = fmaxf(kb.x, cx1), iy1 = fmaxf(kb.y, cy1);
                const float ix2 = fminf(kb.z, cx2), iy2 = fminf(kb.w, cy2);
                const float iw = fmaxf(ix2 - ix1 + 1.0f, 0.0f);
                const float ih = fmaxf(iy2 - iy1 + 1.0f, 0.0f);
                const float inter = iw * ih;
                sup = sup || (inter / (kar + car - inter) > NMS_T);
            }
            uint64_t alive = ~__ballot(sup);
            // Intra-batch serial keep loop (sorted rank order == lane order).
            while (alive != 0ull && kcount < MAXK) {
                const int l = __builtin_ctzll(alive);      // highest-ranked alive
                const float kx1 = __shfl(cx1, l), ky1 = __shfl(cy1, l);
                const float kx2 = __shfl(cx2, l), ky2 = __shfl(cy2, l);
                const float kar = (kx2 - kx1 + 1.0f) * (ky2 - ky1 + 1.0f);
                if (lane == l) {
                    keptL[kcount] = make_float4(cx1, cy1, cx2, cy2);
                    ksc[kcount] = csc;
                }
                if (kcount == 0) cls_best = make_float4(kx1, ky1, kx2, ky2);
                const float ix1 = fmaxf(kx1, cx1), iy1 = fmaxf(ky1, cy1);
                const float ix2 = fminf(kx2, cx2), iy2 = fminf(ky2, cy2);
                const float iw = fmaxf(ix2 - ix1 + 1.0f, 0.0f);
                const float ih = fmaxf(iy2 - iy1 + 1.0f, 0.0f);
                const float inter = iw * ih;
                const bool s2 = (inter / (kar + car - inter) > NMS_T);
                alive &= ~__ballot(s2);
                alive &= ~(1ull << l);     // keeper always removed
                kcount++;
            }
        }

        if (lane == 0) {
            kcounts[obase] = kcount;
            float* cbp = cls_box + obase * 4;
            cbp[0] = cls_best.x; cbp[1] = cls_best.y;
            cbp[2] = cls_best.z; cbp[3] = cls_best.w;
        }
    }
}

// Kernel C: one block per (stream, image): global top-50 cap via branchless
// full count of strictly-greater entries, then the LAST finished block does
// the joint A*B argmax + output gather (device-scope atomic gate).
__global__ __launch_bounds__(64) void select_combine(
    const float* __restrict__ kept_scores, const int* __restrict__ kcounts,
    const float* __restrict__ cls_box,
    const float* __restrict__ rois_A, const float* __restrict__ pred_A,
    const float* __restrict__ info_A,
    const float* __restrict__ rois_B, const float* __restrict__ pred_B,
    const float* __restrict__ info_B,
    int Bimg, int N, int C,
    float* best_s, float* best_b, int* sync_counter, float* __restrict__ out)
{
    const int FG = C - 1;
    const int bx = blockIdx.x;           // st*Bimg + b
    const int st = bx / Bimg;
    const int b  = bx % Bimg;
    const int tid = threadIdx.x;

    __shared__ float sk[20][MAXK];
    __shared__ int   skc[20];
    __shared__ float stopv[20];
    __shared__ int   cnt20[20];
    __shared__ int   inflag[20];
    __shared__ float gbox[4];
    __shared__ int   amlast;

    const size_t base = (size_t)bx * FG;
    for (int i = tid; i < FG * MAXK; i += 64)
        sk[i / MAXK][i % MAXK] = kept_scores[base * MAXK + i];
    if (tid < FG) {
        skc[tid] = kcounts[base + tid];
        cnt20[tid] = 0;
    }
    __syncthreads();
    if (tid < FG)
        stopv[tid] = (skc[tid] > 0) ? sk[tid][0] : -INFINITY;
    __syncthreads();

    // Count entries strictly greater than each class's best (400 pairs over
    // 64 lanes, branchless inner loop -> pipelined LDS reads).
    for (int p = tid; p < FG * FG; p += 64) {
        const int cc = p / FG;     // candidate class
        const int c2 = p % FG;     // donor class
        const float sc = stopv[cc];
        const int k2 = skc[c2];
        int cnt = 0;
        if (skc[cc] > 0) {
            #pragma unroll 5
            for (int k = 0; k < k2; ++k) {
                const float v = sk[c2][k];
                cnt += ((v > sc) || (v == sc && c2 < cc)) ? 1 : 0;
            }
        }
        if (cnt) atomicAdd(&cnt20[cc], cnt);
    }
    __syncthreads();
    if (tid < FG)
        inflag[tid] = (skc[tid] > 0 && cnt20[tid] < MAXK) ? 1 : 0;
    __syncthreads();

    if (tid == 0) {
        int g = -1;
        float bs = -INFINITY;
        for (int c2 = 0; c2 < FG; ++c2)
            if (skc[c2] > 0 && stopv[c2] > bs) { bs = stopv[c2]; g = c2; }
        if (g >= 0) {
            const float* cbp = cls_box + (base + g) * 4;
            gbox[0] = cbp[0]; gbox[1] = cbp[1]; gbox[2] = cbp[2]; gbox[3] = cbp[3];
        } else {
            const float* rois = st ? rois_B : rois_A;
            const float* pred = st ? pred_B : pred_A;
            const float* info = st ? info_B : info_A;
            decode_box(rois, pred, info[b * 3], info[b * 3 + 1], info[b * 3 + 2],
                       b, 0, 1, N, C, gbox);
        }
    }
    __syncthreads();

    if (tid < FG) {
        const int in = inflag[tid];
        best_s[base + tid] = in ? stopv[tid] : -INFINITY;
        float* ob = best_b + (base + tid) * 4;
        if (in) {
            const float* cbp = cls_box + (base + tid) * 4;
            ob[0] = cbp[0]; ob[1] = cbp[1]; ob[2] = cbp[2]; ob[3] = cbp[3];
        } else {
            ob[0] = gbox[0]; ob[1] = gbox[1]; ob[2] = gbox[2]; ob[3] = gbox[3];
        }
    }

    // ---- last-done block performs the combine ----
    __threadfence();
    if (tid == 0) amlast = (atomicAdd(sync_counter, 1) == 2 * Bimg - 1);
    __syncthreads();
    if (amlast) {
        __threadfence();   // acquire: other blocks' best_s/best_b now visible
        if (tid < Bimg) {
            const int i = tid;
            const float* sA = best_s + (size_t)i * FG;
            const float* sB = best_s + (size_t)(Bimg + i) * FG;
            float bj = 0.0f;
            int cls = 0;
            for (int cc = 0; cc < FG; ++cc) {
                const float v = sA[cc] * sB[cc];   // IEEE: -inf*-inf=+inf
                if (cc == 0 || v > bj) { bj = v; cls = cc; }
            }
            const float* bA = best_b + ((size_t)i * FG + cls) * 4;
            const float* bB = best_b + ((size_t)(Bimg + i) * FG + cls) * 4;
            for (int k = 0; k < 4; ++k) {
                out[i * 4 + k]            = bA[k];
                out[Bimg * 4 + i * 4 + k] = bB[k];
            }
        }
    }
}

extern "C" void kernel_launch(void* const* d_in, const int* in_sizes, int n_in,
                              void* d_out, int out_size, void* d_ws, size_t ws_size,
                              hipStream_t stream) {
    const float* rois_A = (const float*)d_in[0];
    const float* cls_A  = (const float*)d_in[1];
    const float* pred_A = (const float*)d_in[2];
    const float* info_A = (const float*)d_in[3];
    const float* rois_B = (const float*)d_in[4];
    const float* cls_B  = (const float*)d_in[5];
    const float* pred_B = (const float*)d_in[6];
    const float* info_B = (const float*)d_in[7];
    float* out = (float*)d_out;

    const int Bimg = in_sizes[3] / 3;                  // 8
    const int N    = in_sizes[0] / (Bimg * 5);         // 2000
    const int C    = in_sizes[1] / (Bimg * N);         // 21
    const int FG   = C - 1;                            // 20
    const int NSB  = 2 * Bimg * FG;                    // 320 tasks

    // Workspace layout
    char* ws = (char*)d_ws;
    int* cnt = (int*)ws;                                   // [320] + sync at [320]
    int* sync_counter = cnt + NSB;
    size_t off = 2048;
    unsigned long long* keys_ws = (unsigned long long*)(ws + off);  // [320][CAP]
    off += (size_t)NSB * CAP * sizeof(unsigned long long);
    float* kept_scores = (float*)(ws + off);               // [320][50]
    off += (size_t)NSB * MAXK * sizeof(float);
    int* kcounts = (int*)(ws + off);                       // [320]
    off += (size_t)NSB * sizeof(int);
    float* cls_box = (float*)(ws + off);                   // [320][4]
    off += (size_t)NSB * 4 * sizeof(float);
    float* best_s = (float*)(ws + off);                    // [320]
    off += (size_t)NSB * sizeof(float);
    float* best_b = (float*)(ws + off);                    // [320][4]

    // Reset append counters + completion counter (graph-capturable).
    hipMemsetAsync(ws, 0, 2048, stream);

    const size_t total = (size_t)2 * Bimg * N * C;
    const int cgrid = (int)((total + BNTH - 1) / BNTH);
    collect_kernel<<<cgrid, BNTH, 0, stream>>>(
        cls_A, cls_B, Bimg, N, C, cnt, keys_ws);

    nms_kernel<<<NSB, BNTH, 0, stream>>>(
        rois_A, pred_A, info_A, rois_B, pred_B, info_B,
        Bimg, N, C, cnt, keys_ws, kept_scores, kcounts, cls_box);

    select_combine<<<2 * Bimg, 64, 0, stream>>>(
        kept_scores, kcounts, cls_box,
        rois_A, pred_A, info_A, rois_B, pred_B, info_B,
        Bimg, N, C, best_s, best_b, sync_counter, out);
}

// Round 6
// 61.589 us; speedup vs baseline: 2.4595x; 2.4595x over previous
//
#include <hip/hip_runtime.h>
#include <stdint.h>
#include <math.h>

#define BNTH 256           // block size (4 waves)
#define CAP 1024           // max candidates per class-task
#define MAXK 50
#define THRESH_F 0.05f
#define NMS_T 0.3f
#define CMAX 24            // max classes supported by collect tile (problem: 21)
#define SEGW_MAX 48        // max 64-row segments per image (problem: 32)

// Decode one (image b, row n, class c) box exactly like the reference:
// bbox_transform_inv + clip + /scale.  (Arithmetic identical to the version
// that passed with absmax 0.0 -- do not reorder.)
__device__ __forceinline__ void decode_box(
    const float* __restrict__ rois, const float* __restrict__ pred,
    float H, float W, float scale,
    int b, int n, int c, int N, int C, float out[4])
{
    const float* r = rois + ((size_t)b * N + n) * 5;
    float bx1 = r[1], by1 = r[2], bx2 = r[3], by2 = r[4];
    float w  = bx2 - bx1 + 1.0f;
    float h  = by2 - by1 + 1.0f;
    float cx = bx1 + 0.5f * w;
    float cy = by1 + 0.5f * h;
    const float* d = pred + ((size_t)b * N + n) * 4 * C + 4 * c;
    float dx = d[0] * 0.1f, dy = d[1] * 0.1f;
    float dw = d[2] * 0.2f, dh = d[3] * 0.2f;
    float pcx = dx * w + cx;
    float pcy = dy * h + cy;
    float pw  = expf(dw) * w;
    float ph  = expf(dh) * h;
    float X1 = fminf(fmaxf(pcx - 0.5f * pw, 0.0f), W - 1.0f);
    float Y1 = fminf(fmaxf(pcy - 0.5f * ph, 0.0f), H - 1.0f);
    float X2 = fminf(fmaxf(pcx + 0.5f * pw, 0.0f), W - 1.0f);
    float Y2 = fminf(fmaxf(pcy + 0.5f * ph, 0.0f), H - 1.0f);
    out[0] = X1 / scale;
    out[1] = Y1 / scale;
    out[2] = X2 / scale;
    out[3] = Y2 / scale;
}

// Kernel A: deterministic segmented collect, ZERO global atomics.
// One wave per (global image, 64-row segment): coalesced tile load to LDS,
// then per class a ballot-compaction into a PRIVATE key segment
// keys_ws[(imgseg)*FG + class][0..64) plus a count.  Wave owns all its
// writes -> no contention, fully deterministic.
__global__ __launch_bounds__(BNTH) void collect_kernel(
    const float* __restrict__ cls_A, const float* __restrict__ cls_B,
    int Bimg, int N, int C, int SEGW,
    int* __restrict__ scnt, unsigned long long* __restrict__ keys_ws)
{
    const int FG = C - 1;
    const int w = threadIdx.x >> 6;
    const int lane = threadIdx.x & 63;
    const int gw = blockIdx.x * 4 + w;          // global wave id
    const int nimg = 2 * Bimg;
    const int ib = gw / SEGW;                   // global image 0..2*Bimg-1
    const int seg = gw % SEGW;
    const bool live = (ib < nimg);

    __shared__ float tile[4][64 * CMAX];

    int n0 = 0, nrows = 0, b = 0, st = 0;
    const float* cls = cls_A;
    if (live) {
        st = ib >= Bimg;
        b = ib - st * Bimg;
        cls = st ? cls_B : cls_A;
        n0 = seg * 64;
        nrows = N - n0; nrows = nrows < 0 ? 0 : (nrows > 64 ? 64 : nrows);
    }

    // Coalesced tile load (rows are contiguous in memory).
    float* tl = tile[w];
    const size_t gbase = ((size_t)b * N + n0) * C;
    const int tot = nrows * C;
    for (int e = lane; e < tot; e += 64) tl[e] = cls[gbase + e];
    __syncthreads();   // orders LDS writes vs cross-lane reads (cheap)

    if (live) {
        for (int cc = 1; cc < C; ++cc) {
            // lane -> row n0+lane; stride-C word access: 2-way bank alias (free)
            const float sc = (lane < nrows) ? tl[lane * C + cc] : 0.0f;
            const bool val = sc > THRESH_F;
            const uint64_t bal = __ballot(val);
            const size_t task_seg = (size_t)(ib * SEGW + seg) * FG + (cc - 1);
            if (val) {
                const int slot = __popcll(bal & ((1ull << lane) - 1ull));
                keys_ws[task_seg * 64 + slot] =
                    ((uint64_t)__float_as_uint(sc) << 32) |
                    (uint32_t)(~(uint32_t)(n0 + lane));
            }
            if (lane == 0) scnt[task_seg] = __popcll(bal);
        }
    }
}

// Register bitonic sort, descending, over SN elements laid out as
// index i = s*64 + lane (slot-major), on ONE wave.  Keys are u64
// (score<<32|~row) reinterpreted as POSITIVE doubles (exponent normal,
// never NaN), so f64 fmax/fmin ordering == u64 ordering.
template<int SN>
__device__ __forceinline__ void bitonic_desc(double* kd, int lane)
{
    constexpr int NS = SN / 64;
    #pragma unroll
    for (int k = 2; k <= SN; k <<= 1) {
        #pragma unroll
        for (int j = k >> 1; j >= 1; j >>= 1) {
            if (j >= 64) {
                const int js = j >> 6;
                #pragma unroll
                for (int s = 0; s < NS; ++s) {
                    if ((s & js) == 0) {
                        const int sp = s | js;
                        const bool d = (((s << 6) & k) == 0);  // compile-time
                        const double a = kd[s], bb = kd[sp];
                        kd[s]  = d ? fmax(a, bb) : fmin(a, bb);
                        kd[sp] = d ? fmin(a, bb) : fmax(a, bb);
                    }
                }
            } else {
                #pragma unroll
                for (int s = 0; s < NS; ++s) {
                    const double o = __shfl_xor(kd[s], j);
                    const bool lower = (lane & j) == 0;
                    const bool d = ((((s << 6) | lane) & k) == 0);
                    const bool takeMax = (d == lower);
                    const double mx = fmax(kd[s], o);
                    const double mn = fmin(kd[s], o);
                    kd[s] = takeMax ? mx : mn;
                }
            }
        }
    }
}

// Kernel B: one 4-wave block per (stream, image, fg-class).
// segment prefix-sum -> parallel gather of keys -> wave-0 register sort ->
// all-wave decode in sorted order -> wave-0 sorted-scan NMS.
__global__ __launch_bounds__(BNTH, 1) void nms_kernel(
    const float* __restrict__ rois_A, const float* __restrict__ pred_A,
    const float* __restrict__ info_A,
    const float* __restrict__ rois_B, const float* __restrict__ pred_B,
    const float* __restrict__ info_B,
    int Bimg, int N, int C, int SEGW,
    const int* __restrict__ scnt, const unsigned long long* __restrict__ keys_ws,
    float* __restrict__ kept_scores, int* __restrict__ kcounts,
    float* __restrict__ cls_box, int* __restrict__ sync_counter)
{
    const int FG = C - 1;
    const int bx = blockIdx.x;
    const int st  = bx / (Bimg * FG);
    const int rem = bx % (Bimg * FG);
    const int b = rem / FG;
    const int j = rem % FG;
    const int c = j + 1;
    const int tid = threadIdx.x;
    const int lane = tid & 63;
    const int ib = st * Bimg + b;

    if (bx == 0 && tid == 0) *sync_counter = 0;   // ordered before select

    const float* rois = st ? rois_B : rois_A;
    const float* pred = st ? pred_B : pred_A;
    const float* info = st ? info_B : info_A;

    __shared__ uint64_t keysL[CAP];
    __shared__ float4 boxL[CAP];
    __shared__ float  sarL[CAP];
    __shared__ float4 keptL[MAXK];
    __shared__ int offL[SEGW_MAX + 1];

    // ---- Segment counts -> exclusive offsets (wave 0 shfl scan) ----
    if (tid < 64) {
        int v = 0;
        if (lane < SEGW) v = scnt[(size_t)(ib * SEGW + lane) * FG + j];
        #pragma unroll
        for (int d = 1; d < 64; d <<= 1) {
            const int o = __shfl_up(v, d);
            if (lane >= d) v += o;
        }
        if (lane < SEGW) offL[lane + 1] = v;
        if (lane == 0) offL[0] = 0;
    }
    __syncthreads();
    const int Mfull = offL[SEGW];
    const int M = Mfull < CAP ? Mfull : CAP;

    // ---- Parallel key gather via binary search over offsets ----
    for (int i = tid; i < CAP; i += BNTH) {
        uint64_t k = 0ull;
        if (i < M) {
            int lo = 0, hi = SEGW;          // offL[lo] <= i < offL[hi]
            while (hi - lo > 1) {
                const int mid = (lo + hi) >> 1;
                if (offL[mid] <= i) lo = mid; else hi = mid;
            }
            k = keys_ws[((size_t)(ib * SEGW + lo) * FG + j) * 64 + (i - offL[lo])];
        }
        keysL[i] = k;
    }
    __syncthreads();

    // ---- Sort descending on wave 0 (registers; smallest sufficient net) ----
    if (tid < 64) {
        if (M > 1) {
            if (M <= 512) {
                double kd[8];
                #pragma unroll
                for (int s = 0; s < 8; ++s)
                    kd[s] = __longlong_as_double((long long)keysL[s * 64 + lane]);
                bitonic_desc<512>(kd, lane);
                #pragma unroll
                for (int s = 0; s < 8; ++s)
                    keysL[s * 64 + lane] = (uint64_t)__double_as_longlong(kd[s]);
            } else {
                double kd[16];
                #pragma unroll
                for (int s = 0; s < 16; ++s)
                    kd[s] = __longlong_as_double((long long)keysL[s * 64 + lane]);
                bitonic_desc<1024>(kd, lane);
                #pragma unroll
                for (int s = 0; s < 16; ++s)
                    keysL[s * 64 + lane] = (uint64_t)__double_as_longlong(kd[s]);
            }
        }
    }
    __syncthreads();

    // ---- Decode in SORTED order, all 4 waves (4x latency hiding) ----
    const float H = info[b * 3 + 0];
    const float W = info[b * 3 + 1];
    const float scale = info[b * 3 + 2];
    for (int i = tid; i < M; i += BNTH) {
        const uint64_t u = keysL[i];
        const int n = (int)(~(uint32_t)u);
        float o[4];
        decode_box(rois, pred, H, W, scale, b, n, c, N, C, o);
        boxL[i] = make_float4(o[0], o[1], o[2], o[3]);
        sarL[i] = (o[2] - o[0] + 1.0f) * (o[3] - o[1] + 1.0f);
    }
    __syncthreads();

    // ---- Scan NMS over sorted order on wave 0, 64 candidates per batch ----
    if (tid < 64) {
        float* ksc = kept_scores + (size_t)bx * MAXK;
        int kcount = 0;
        float4 cls_best = make_float4(0.f, 0.f, 0.f, 0.f);

        for (int s = 0; s * 64 < M && kcount < MAXK; ++s) {
            const int ii = s * 64 + lane;
            const bool valid = (ii < M);
            float cx1 = 0.f, cy1 = 0.f, cx2 = 0.f, cy2 = 0.f, car = 1.0f, csc = 0.f;
            if (valid) {
                const float4 cb4 = boxL[ii];
                cx1 = cb4.x; cy1 = cb4.y; cx2 = cb4.z; cy2 = cb4.w;
                car = sarL[ii];
                csc = __uint_as_float((uint32_t)(keysL[ii] >> 32));
            }
            // Pre-suppression vs already-kept boxes (uniform loop, pipelined).
            bool sup = !valid;
            for (int q = 0; q < kcount; ++q) {
                const float4 kb = keptL[q];
                const float kar = (kb.z - kb.x + 1.0f) * (kb.w - kb.y + 1.0f);
                const float ix1 = fmaxf(kb.x, cx1), iy1 = fmaxf(kb.y, cy1);
                const float ix2 = fminf(kb.z, cx2), iy2 = fminf(kb.w, cy2);
                const float iw = fmaxf(ix2 - ix1 + 1.0f, 0.0f);
                const float ih = fmaxf(iy2 - iy1 + 1.0f, 0.0f);
                const float inter = iw * ih;
                sup = sup || (inter / (kar + car - inter) > NMS_T);
            }
            uint64_t alive = ~__ballot(sup);
            // Intra-batch serial keep loop (sorted rank order == lane order).
            while (alive != 0ull && kcount < MAXK) {
                const int l = __builtin_ctzll(alive);      // highest-ranked alive
                const float kx1 = __shfl(cx1, l), ky1 = __shfl(cy1, l);
                const float kx2 = __shfl(cx2, l), ky2 = __shfl(cy2, l);
                const float kar = (kx2 - kx1 + 1.0f) * (ky2 - ky1 + 1.0f);
                if (lane == l) {
                    keptL[kcount] = make_float4(cx1, cy1, cx2, cy2);
                    ksc[kcount] = csc;
                }
                if (kcount == 0) cls_best = make_float4(kx1, ky1, kx2, ky2);
                const float ix1 = fmaxf(kx1, cx1), iy1 = fmaxf(ky1, cy1);
                const float ix2 = fminf(kx2, cx2), iy2 = fminf(ky2, cy2);
                const float iw = fmaxf(ix2 - ix1 + 1.0f, 0.0f);
                const float ih = fmaxf(iy2 - iy1 + 1.0f, 0.0f);
                const float inter = iw * ih;
                const bool s2 = (inter / (kar + car - inter) > NMS_T);
                alive &= ~__ballot(s2);
                alive &= ~(1ull << l);     // keeper always removed
                kcount++;
            }
        }

        if (lane == 0) {
            kcounts[bx] = kcount;
            float* cbp = cls_box + (size_t)bx * 4;
            cbp[0] = cls_best.x; cbp[1] = cls_best.y;
            cbp[2] = cls_best.z; cbp[3] = cls_best.w;
        }
    }
}

// Kernel C: one block per (stream, image): global top-50 cap via branchless
// full count of strictly-greater entries, then the LAST finished block does
// the joint A*B argmax + output gather (device-scope atomic gate).
__global__ __launch_bounds__(64) void select_combine(
    const float* __restrict__ kept_scores, const int* __restrict__ kcounts,
    const float* __restrict__ cls_box,
    const float* __restrict__ rois_A, const float* __restrict__ pred_A,
    const float* __restrict__ info_A,
    const float* __restrict__ rois_B, const float* __restrict__ pred_B,
    const float* __restrict__ info_B,
    int Bimg, int N, int C,
    float* best_s, float* best_b, int* sync_counter, float* __restrict__ out)
{
    const int FG = C - 1;
    const int bx = blockIdx.x;           // st*Bimg + b
    const int st = bx / Bimg;
    const int b  = bx % Bimg;
    const int tid = threadIdx.x;

    __shared__ float sk[20][MAXK];
    __shared__ int   skc[20];
    __shared__ float stopv[20];
    __shared__ int   cnt20[20];
    __shared__ int   inflag[20];
    __shared__ float gbox[4];
    __shared__ int   amlast;

    const size_t base = (size_t)bx * FG;
    for (int i = tid; i < FG * MAXK; i += 64)
        sk[i / MAXK][i % MAXK] = kept_scores[base * MAXK + i];
    if (tid < FG) {
        skc[tid] = kcounts[base + tid];
        cnt20[tid] = 0;
    }
    __syncthreads();
    if (tid < FG)
        stopv[tid] = (skc[tid] > 0) ? sk[tid][0] : -INFINITY;
    __syncthreads();

    // Count entries strictly greater than each class's best (400 pairs over
    // 64 lanes, branchless inner loop -> pipelined LDS reads).
    for (int p = tid; p < FG * FG; p += 64) {
        const int cc = p / FG;     // candidate class
        const int c2 = p % FG;     // donor class
        const float sc = stopv[cc];
        const int k2 = skc[c2];
        int cnt = 0;
        if (skc[cc] > 0) {
            #pragma unroll 5
            for (int k = 0; k < k2; ++k) {
                const float v = sk[c2][k];
                cnt += ((v > sc) || (v == sc && c2 < cc)) ? 1 : 0;
            }
        }
        if (cnt) atomicAdd(&cnt20[cc], cnt);
    }
    __syncthreads();
    if (tid < FG)
        inflag[tid] = (skc[tid] > 0 && cnt20[tid] < MAXK) ? 1 : 0;
    __syncthreads();

    if (tid == 0) {
        int g = -1;
        float bs = -INFINITY;
        for (int c2 = 0; c2 < FG; ++c2)
            if (skc[c2] > 0 && stopv[c2] > bs) { bs = stopv[c2]; g = c2; }
        if (g >= 0) {
            const float* cbp = cls_box + (base + g) * 4;
            gbox[0] = cbp[0]; gbox[1] = cbp[1]; gbox[2] = cbp[2]; gbox[3] = cbp[3];
        } else {
            const float* rois = st ? rois_B : rois_A;
            const float* pred = st ? pred_B : pred_A;
            const float* info = st ? info_B : info_A;
            decode_box(rois, pred, info[b * 3], info[b * 3 + 1], info[b * 3 + 2],
                       b, 0, 1, N, C, gbox);
        }
    }
    __syncthreads();

    if (tid < FG) {
        const int in = inflag[tid];
        best_s[base + tid] = in ? stopv[tid] : -INFINITY;
        float* ob = best_b + (base + tid) * 4;
        if (in) {
            const float* cbp = cls_box + (base + tid) * 4;
            ob[0] = cbp[0]; ob[1] = cbp[1]; ob[2] = cbp[2]; ob[3] = cbp[3];
        } else {
            ob[0] = gbox[0]; ob[1] = gbox[1]; ob[2] = gbox[2]; ob[3] = gbox[3];
        }
    }

    // ---- last-done block performs the combine ----
    __threadfence();
    if (tid == 0) amlast = (atomicAdd(sync_counter, 1) == 2 * Bimg - 1);
    __syncthreads();
    if (amlast) {
        __threadfence();   // acquire: other blocks' best_s/best_b now visible
        if (tid < Bimg) {
            const int i = tid;
            const float* sA = best_s + (size_t)i * FG;
            const float* sB = best_s + (size_t)(Bimg + i) * FG;
            float bj = 0.0f;
            int cls = 0;
            for (int cc = 0; cc < FG; ++cc) {
                const float v = sA[cc] * sB[cc];   // IEEE: -inf*-inf=+inf
                if (cc == 0 || v > bj) { bj = v; cls = cc; }
            }
            const float* bA = best_b + ((size_t)i * FG + cls) * 4;
            const float* bB = best_b + ((size_t)(Bimg + i) * FG + cls) * 4;
            for (int k = 0; k < 4; ++k) {
                out[i * 4 + k]            = bA[k];
                out[Bimg * 4 + i * 4 + k] = bB[k];
            }
        }
    }
}

extern "C" void kernel_launch(void* const* d_in, const int* in_sizes, int n_in,
                              void* d_out, int out_size, void* d_ws, size_t ws_size,
                              hipStream_t stream) {
    const float* rois_A = (const float*)d_in[0];
    const float* cls_A  = (const float*)d_in[1];
    const float* pred_A = (const float*)d_in[2];
    const float* info_A = (const float*)d_in[3];
    const float* rois_B = (const float*)d_in[4];
    const float* cls_B  = (const float*)d_in[5];
    const float* pred_B = (const float*)d_in[6];
    const float* info_B = (const float*)d_in[7];
    float* out = (float*)d_out;

    const int Bimg = in_sizes[3] / 3;                  // 8
    const int N    = in_sizes[0] / (Bimg * 5);         // 2000
    const int C    = in_sizes[1] / (Bimg * N);         // 21
    const int FG   = C - 1;                            // 20
    const int NSB  = 2 * Bimg * FG;                    // 320 tasks
    const int SEGW = (N + 63) / 64;                    // 32 segments/image

    // Workspace layout (no resets needed: everything is overwritten each call)
    char* ws = (char*)d_ws;
    int* sync_counter = (int*)ws;
    size_t off = 256;
    int* scnt = (int*)(ws + off);                          // [2B*SEGW*FG]
    off += (size_t)2 * Bimg * SEGW * FG * sizeof(int);
    off = (off + 255) & ~(size_t)255;
    unsigned long long* keys_ws = (unsigned long long*)(ws + off);  // [2B*SEGW*FG][64]
    off += (size_t)2 * Bimg * SEGW * FG * 64 * sizeof(unsigned long long);
    float* kept_scores = (float*)(ws + off);               // [320][50]
    off += (size_t)NSB * MAXK * sizeof(float);
    int* kcounts = (int*)(ws + off);                       // [320]
    off += (size_t)NSB * sizeof(int);
    float* cls_box = (float*)(ws + off);                   // [320][4]
    off += (size_t)NSB * 4 * sizeof(float);
    float* best_s = (float*)(ws + off);                    // [320]
    off += (size_t)NSB * sizeof(float);
    float* best_b = (float*)(ws + off);                    // [320][4]

    const int nwaves = 2 * Bimg * SEGW;
    collect_kernel<<<(nwaves + 3) / 4, BNTH, 0, stream>>>(
        cls_A, cls_B, Bimg, N, C, SEGW, scnt, keys_ws);

    nms_kernel<<<NSB, BNTH, 0, stream>>>(
        rois_A, pred_A, info_A, rois_B, pred_B, info_B,
        Bimg, N, C, SEGW, scnt, keys_ws, kept_scores, kcounts, cls_box,
        sync_counter);

    select_combine<<<2 * Bimg, 64, 0, stream>>>(
        kept_scores, kcounts, cls_box,
        rois_A, pred_A, info_A, rois_B, pred_B, info_B,
        Bimg, N, C, best_s, best_b, sync_counter, out);
}

// Round 7
// 60.480 us; speedup vs baseline: 2.5046x; 1.0183x over previous
//
#include <hip/hip_runtime.h>
#include <stdint.h>
#include <math.h>

#define BNTH 256           // 4 waves
#define CAP 1024           // max candidates per class-task
#define MAXK 50
#define THRESH_F 0.05f
#define NMS_T 0.3f
#define SEGW_MAX 48        // max 64-row segments per image (problem: 32)

// Decode one (image b, row n, class c) box exactly like the reference:
// bbox_transform_inv + clip + /scale.  (Arithmetic identical to the version
// that passed with absmax 0.0 -- do not reorder.)
__device__ __forceinline__ void decode_box(
    const float* __restrict__ rois, const float* __restrict__ pred,
    float H, float W, float scale,
    int b, int n, int c, int N, int C, float out[4])
{
    const float* r = rois + ((size_t)b * N + n) * 5;
    float bx1 = r[1], by1 = r[2], bx2 = r[3], by2 = r[4];
    float w  = bx2 - bx1 + 1.0f;
    float h  = by2 - by1 + 1.0f;
    float cx = bx1 + 0.5f * w;
    float cy = by1 + 0.5f * h;
    const float* d = pred + ((size_t)b * N + n) * 4 * C + 4 * c;
    float dx = d[0] * 0.1f, dy = d[1] * 0.1f;
    float dw = d[2] * 0.2f, dh = d[3] * 0.2f;
    float pcx = dx * w + cx;
    float pcy = dy * h + cy;
    float pw  = expf(dw) * w;
    float ph  = expf(dh) * h;
    float X1 = fminf(fmaxf(pcx - 0.5f * pw, 0.0f), W - 1.0f);
    float Y1 = fminf(fmaxf(pcy - 0.5f * ph, 0.0f), H - 1.0f);
    float X2 = fminf(fmaxf(pcx + 0.5f * pw, 0.0f), W - 1.0f);
    float Y2 = fminf(fmaxf(pcy + 0.5f * ph, 0.0f), H - 1.0f);
    out[0] = X1 / scale;
    out[1] = Y1 / scale;
    out[2] = X2 / scale;
    out[3] = Y2 / scale;
}

// Register bitonic sort, descending, over SN elements laid out as
// index i = s*64 + lane (slot-major), on ONE wave.  Keys are u64
// (score<<32|~row) reinterpreted as POSITIVE doubles (exponent normal,
// never NaN), so f64 fmax/fmin ordering == u64 ordering.
template<int SN>
__device__ __forceinline__ void bitonic_desc(double* kd, int lane)
{
    constexpr int NS = SN / 64;
    #pragma unroll
    for (int k = 2; k <= SN; k <<= 1) {
        #pragma unroll
        for (int j = k >> 1; j >= 1; j >>= 1) {
            if (j >= 64) {
                const int js = j >> 6;
                #pragma unroll
                for (int s = 0; s < NS; ++s) {
                    if ((s & js) == 0) {
                        const int sp = s | js;
                        const bool d = (((s << 6) & k) == 0);  // compile-time
                        const double a = kd[s], bb = kd[sp];
                        kd[s]  = d ? fmax(a, bb) : fmin(a, bb);
                        kd[sp] = d ? fmin(a, bb) : fmax(a, bb);
                    }
                }
            } else {
                #pragma unroll
                for (int s = 0; s < NS; ++s) {
                    const double o = __shfl_xor(kd[s], j);
                    const bool lower = (lane & j) == 0;
                    const bool d = ((((s << 6) | lane) & k) == 0);
                    const bool takeMax = (d == lower);
                    const double mx = fmax(kd[s], o);
                    const double mn = fmin(kd[s], o);
                    kd[s] = takeMax ? mx : mn;
                }
            }
        }
    }
}

// Kernel 1 (FUSED): one 4-wave block per (stream, image, fg-class).
// In-block collect (direct strided score reads, per-wave-segment ballot
// compaction in LDS, shfl prefix scan, gather) -> wave-0 register sort ->
// all-wave decode in sorted order -> wave-0 sorted-scan NMS.
// Zero global atomics; fully deterministic.
__global__ __launch_bounds__(BNTH, 1) void nms_kernel(
    const float* __restrict__ rois_A, const float* __restrict__ cls_A,
    const float* __restrict__ pred_A, const float* __restrict__ info_A,
    const float* __restrict__ rois_B, const float* __restrict__ cls_B,
    const float* __restrict__ pred_B, const float* __restrict__ info_B,
    int Bimg, int N, int C,
    float* __restrict__ kept_scores, int* __restrict__ kcounts,
    float* __restrict__ cls_box, int* __restrict__ sync_counter)
{
    const int FG = C - 1;
    const int bx = blockIdx.x;
    const int st  = bx / (Bimg * FG);
    const int rem = bx % (Bimg * FG);
    const int b = rem / FG;
    const int j = rem % FG;
    const int c = j + 1;
    const int tid = threadIdx.x;
    const int w = tid >> 6;
    const int lane = tid & 63;
    const int SEGW = (N + 63) >> 6;              // 64-row segments (32)

    if (bx == 0 && tid == 0) *sync_counter = 0;  // ordered before kernel 2

    const float* rois = st ? rois_B : rois_A;
    const float* cls  = st ? cls_B  : cls_A;
    const float* pred = st ? pred_B : pred_A;
    const float* info = st ? info_B : info_A;

    __shared__ uint64_t segKeys[SEGW_MAX][64];
    __shared__ int segCnt[SEGW_MAX];
    __shared__ int offL[SEGW_MAX + 1];
    __shared__ uint64_t keysL[CAP];
    __shared__ float4 boxL[CAP];
    __shared__ float  sarL[CAP];
    __shared__ float4 keptL[MAXK];

    // ---- Collect: per-wave segment ballot compaction (no atomics) ----
    // Wave w, round r owns segment seg = w + 4*r; row = seg*64 + lane.
    const int ROUNDS = (SEGW + 3) >> 2;
    for (int r = 0; r < ROUNDS; ++r) {
        const int seg = w + 4 * r;
        if (seg < SEGW) {
            const int n = seg * 64 + lane;
            float sc = 0.0f;
            if (n < N) sc = cls[((size_t)b * N + n) * C + c];
            const bool val = sc > THRESH_F;
            const uint64_t bal = __ballot(val);
            if (val) {
                const int slot = __popcll(bal & ((1ull << lane) - 1ull));
                segKeys[seg][slot] =
                    ((uint64_t)__float_as_uint(sc) << 32) |
                    (uint32_t)(~(uint32_t)n);
            }
            if (lane == 0) segCnt[seg] = __popcll(bal);
        }
    }
    __syncthreads();

    // ---- Segment counts -> exclusive offsets (wave-0 shfl scan) ----
    if (tid < 64) {
        int v = (lane < SEGW) ? segCnt[lane] : 0;
        #pragma unroll
        for (int d = 1; d < 64; d <<= 1) {
            const int o = __shfl_up(v, d);
            if (lane >= d) v += o;
        }
        if (lane < SEGW) offL[lane + 1] = v;
        if (lane == 0) offL[0] = 0;
    }
    __syncthreads();
    const int Mfull = offL[SEGW];
    const int M = Mfull < CAP ? Mfull : CAP;

    // ---- Gather segments -> contiguous keysL (binary search, all waves) ----
    for (int i = tid; i < CAP; i += BNTH) {
        uint64_t k = 0ull;
        if (i < M) {
            int lo = 0, hi = SEGW;          // offL[lo] <= i < offL[hi]
            while (hi - lo > 1) {
                const int mid = (lo + hi) >> 1;
                if (offL[mid] <= i) lo = mid; else hi = mid;
            }
            k = segKeys[lo][i - offL[lo]];
        }
        keysL[i] = k;
    }
    __syncthreads();

    // ---- Sort descending on wave 0 (registers; smallest sufficient net) ----
    if (tid < 64) {
        if (M > 1) {
            if (M <= 512) {
                double kd[8];
                #pragma unroll
                for (int s = 0; s < 8; ++s)
                    kd[s] = __longlong_as_double((long long)keysL[s * 64 + lane]);
                bitonic_desc<512>(kd, lane);
                #pragma unroll
                for (int s = 0; s < 8; ++s)
                    keysL[s * 64 + lane] = (uint64_t)__double_as_longlong(kd[s]);
            } else {
                double kd[16];
                #pragma unroll
                for (int s = 0; s < 16; ++s)
                    kd[s] = __longlong_as_double((long long)keysL[s * 64 + lane]);
                bitonic_desc<1024>(kd, lane);
                #pragma unroll
                for (int s = 0; s < 16; ++s)
                    keysL[s * 64 + lane] = (uint64_t)__double_as_longlong(kd[s]);
            }
        }
    }
    __syncthreads();

    // ---- Decode in SORTED order, all 4 waves (4x latency hiding) ----
    const float H = info[b * 3 + 0];
    const float W = info[b * 3 + 1];
    const float scale = info[b * 3 + 2];
    for (int i = tid; i < M; i += BNTH) {
        const uint64_t u = keysL[i];
        const int n = (int)(~(uint32_t)u);
        float o[4];
        decode_box(rois, pred, H, W, scale, b, n, c, N, C, o);
        boxL[i] = make_float4(o[0], o[1], o[2], o[3]);
        sarL[i] = (o[2] - o[0] + 1.0f) * (o[3] - o[1] + 1.0f);
    }
    __syncthreads();

    // ---- Scan NMS over sorted order on wave 0, 64 candidates per batch ----
    if (tid < 64) {
        float* ksc = kept_scores + (size_t)bx * MAXK;
        int kcount = 0;
        float4 cls_best = make_float4(0.f, 0.f, 0.f, 0.f);

        for (int s = 0; s * 64 < M && kcount < MAXK; ++s) {
            const int ii = s * 64 + lane;
            const bool valid = (ii < M);
            float cx1 = 0.f, cy1 = 0.f, cx2 = 0.f, cy2 = 0.f, car = 1.0f, csc = 0.f;
            if (valid) {
                const float4 cb4 = boxL[ii];
                cx1 = cb4.x; cy1 = cb4.y; cx2 = cb4.z; cy2 = cb4.w;
                car = sarL[ii];
                csc = __uint_as_float((uint32_t)(keysL[ii] >> 32));
            }
            // Pre-suppression vs already-kept boxes (uniform loop, pipelined).
            bool sup = !valid;
            for (int q = 0; q < kcount; ++q) {
                const float4 kb = keptL[q];
                const float kar = (kb.z - kb.x + 1.0f) * (kb.w - kb.y + 1.0f);
                const float ix1 = fmaxf(kb.x, cx1), iy1 = fmaxf(kb.y, cy1);
                const float ix2 = fminf(kb.z, cx2), iy2 = fminf(kb.w, cy2);
                const float iw = fmaxf(ix2 - ix1 + 1.0f, 0.0f);
                const float ih = fmaxf(iy2 - iy1 + 1.0f, 0.0f);
                const float inter = iw * ih;
                sup = sup || (inter / (kar + car - inter) > NMS_T);
            }
            uint64_t alive = ~__ballot(sup);
            // Intra-batch serial keep loop (sorted rank order == lane order).
            while (alive != 0ull && kcount < MAXK) {
                const int l = __builtin_ctzll(alive);      // highest-ranked alive
                const float kx1 = __shfl(cx1, l), ky1 = __shfl(cy1, l);
                const float kx2 = __shfl(cx2, l), ky2 = __shfl(cy2, l);
                const float kar = (kx2 - kx1 + 1.0f) * (ky2 - ky1 + 1.0f);
                if (lane == l) {
                    keptL[kcount] = make_float4(cx1, cy1, cx2, cy2);
                    ksc[kcount] = csc;
                }
                if (kcount == 0) cls_best = make_float4(kx1, ky1, kx2, ky2);
                const float ix1 = fmaxf(kx1, cx1), iy1 = fmaxf(ky1, cy1);
                const float ix2 = fminf(kx2, cx2), iy2 = fminf(ky2, cy2);
                const float iw = fmaxf(ix2 - ix1 + 1.0f, 0.0f);
                const float ih = fmaxf(iy2 - iy1 + 1.0f, 0.0f);
                const float inter = iw * ih;
                const bool s2 = (inter / (kar + car - inter) > NMS_T);
                alive &= ~__ballot(s2);
                alive &= ~(1ull << l);     // keeper always removed
                kcount++;
            }
        }

        if (lane == 0) {
            kcounts[bx] = kcount;
            float* cbp = cls_box + (size_t)bx * 4;
            cbp[0] = cls_best.x; cbp[1] = cls_best.y;
            cbp[2] = cls_best.z; cbp[3] = cls_best.w;
        }
    }
}

// Kernel 2: one block per (stream, image): global top-50 cap via branchless
// full count of strictly-greater entries, then the LAST finished block does
// the joint A*B argmax + output gather (device-scope atomic gate).
__global__ __launch_bounds__(64) void select_combine(
    const float* __restrict__ kept_scores, const int* __restrict__ kcounts,
    const float* __restrict__ cls_box,
    const float* __restrict__ rois_A, const float* __restrict__ pred_A,
    const float* __restrict__ info_A,
    const float* __restrict__ rois_B, const float* __restrict__ pred_B,
    const float* __restrict__ info_B,
    int Bimg, int N, int C,
    float* best_s, float* best_b, int* sync_counter, float* __restrict__ out)
{
    const int FG = C - 1;
    const int bx = blockIdx.x;           // st*Bimg + b
    const int st = bx / Bimg;
    const int b  = bx % Bimg;
    const int tid = threadIdx.x;

    __shared__ float sk[20][MAXK];
    __shared__ int   skc[20];
    __shared__ float stopv[20];
    __shared__ int   cnt20[20];
    __shared__ int   inflag[20];
    __shared__ float gbox[4];
    __shared__ int   amlast;

    const size_t base = (size_t)bx * FG;
    for (int i = tid; i < FG * MAXK; i += 64)
        sk[i / MAXK][i % MAXK] = kept_scores[base * MAXK + i];
    if (tid < FG) {
        skc[tid] = kcounts[base + tid];
        cnt20[tid] = 0;
    }
    __syncthreads();
    if (tid < FG)
        stopv[tid] = (skc[tid] > 0) ? sk[tid][0] : -INFINITY;
    __syncthreads();

    // Count entries strictly greater than each class's best (400 pairs over
    // 64 lanes, branchless inner loop -> pipelined LDS reads).
    for (int p = tid; p < FG * FG; p += 64) {
        const int cc = p / FG;     // candidate class
        const int c2 = p % FG;     // donor class
        const float sc = stopv[cc];
        const int k2 = skc[c2];
        int cnt = 0;
        if (skc[cc] > 0) {
            #pragma unroll 5
            for (int k = 0; k < k2; ++k) {
                const float v = sk[c2][k];
                cnt += ((v > sc) || (v == sc && c2 < cc)) ? 1 : 0;
            }
        }
        if (cnt) atomicAdd(&cnt20[cc], cnt);
    }
    __syncthreads();
    if (tid < FG)
        inflag[tid] = (skc[tid] > 0 && cnt20[tid] < MAXK) ? 1 : 0;
    __syncthreads();

    if (tid == 0) {
        int g = -1;
        float bs = -INFINITY;
        for (int c2 = 0; c2 < FG; ++c2)
            if (skc[c2] > 0 && stopv[c2] > bs) { bs = stopv[c2]; g = c2; }
        if (g >= 0) {
            const float* cbp = cls_box + (base + g) * 4;
            gbox[0] = cbp[0]; gbox[1] = cbp[1]; gbox[2] = cbp[2]; gbox[3] = cbp[3];
        } else {
            const float* rois = st ? rois_B : rois_A;
            const float* pred = st ? pred_B : pred_A;
            const float* info = st ? info_B : info_A;
            decode_box(rois, pred, info[b * 3], info[b * 3 + 1], info[b * 3 + 2],
                       b, 0, 1, N, C, gbox);
        }
    }
    __syncthreads();

    if (tid < FG) {
        const int in = inflag[tid];
        best_s[base + tid] = in ? stopv[tid] : -INFINITY;
        float* ob = best_b + (base + tid) * 4;
        if (in) {
            const float* cbp = cls_box + (base + tid) * 4;
            ob[0] = cbp[0]; ob[1] = cbp[1]; ob[2] = cbp[2]; ob[3] = cbp[3];
        } else {
            ob[0] = gbox[0]; ob[1] = gbox[1]; ob[2] = gbox[2]; ob[3] = gbox[3];
        }
    }

    // ---- last-done block performs the combine ----
    __threadfence();
    if (tid == 0) amlast = (atomicAdd(sync_counter, 1) == 2 * Bimg - 1);
    __syncthreads();
    if (amlast) {
        __threadfence();   // acquire: other blocks' best_s/best_b now visible
        if (tid < Bimg) {
            const int i = tid;
            const float* sA = best_s + (size_t)i * FG;
            const float* sB = best_s + (size_t)(Bimg + i) * FG;
            float bj = 0.0f;
            int cls = 0;
            for (int cc = 0; cc < FG; ++cc) {
                const float v = sA[cc] * sB[cc];   // IEEE: -inf*-inf=+inf
                if (cc == 0 || v > bj) { bj = v; cls = cc; }
            }
            const float* bA = best_b + ((size_t)i * FG + cls) * 4;
            const float* bB = best_b + ((size_t)(Bimg + i) * FG + cls) * 4;
            for (int k = 0; k < 4; ++k) {
                out[i * 4 + k]            = bA[k];
                out[Bimg * 4 + i * 4 + k] = bB[k];
            }
        }
    }
}

extern "C" void kernel_launch(void* const* d_in, const int* in_sizes, int n_in,
                              void* d_out, int out_size, void* d_ws, size_t ws_size,
                              hipStream_t stream) {
    const float* rois_A = (const float*)d_in[0];
    const float* cls_A  = (const float*)d_in[1];
    const float* pred_A = (const float*)d_in[2];
    const float* info_A = (const float*)d_in[3];
    const float* rois_B = (const float*)d_in[4];
    const float* cls_B  = (const float*)d_in[5];
    const float* pred_B = (const float*)d_in[6];
    const float* info_B = (const float*)d_in[7];
    float* out = (float*)d_out;

    const int Bimg = in_sizes[3] / 3;                  // 8
    const int N    = in_sizes[0] / (Bimg * 5);         // 2000
    const int C    = in_sizes[1] / (Bimg * N);         // 21
    const int FG   = C - 1;                            // 20
    const int NSB  = 2 * Bimg * FG;                    // 320 tasks

    // Workspace layout (everything overwritten each call; no resets needed)
    char* ws = (char*)d_ws;
    int* sync_counter = (int*)ws;
    size_t off = 256;
    float* kept_scores = (float*)(ws + off);               // [320][50]
    off += (size_t)NSB * MAXK * sizeof(float);
    int* kcounts = (int*)(ws + off);                       // [320]
    off += (size_t)NSB * sizeof(int);
    float* cls_box = (float*)(ws + off);                   // [320][4]
    off += (size_t)NSB * 4 * sizeof(float);
    float* best_s = (float*)(ws + off);                    // [320]
    off += (size_t)NSB * sizeof(float);
    float* best_b = (float*)(ws + off);                    // [320][4]

    nms_kernel<<<NSB, BNTH, 0, stream>>>(
        rois_A, cls_A, pred_A, info_A,
        rois_B, cls_B, pred_B, info_B,
        Bimg, N, C, kept_scores, kcounts, cls_box, sync_counter);

    select_combine<<<2 * Bimg, 64, 0, stream>>>(
        kept_scores, kcounts, cls_box,
        rois_A, pred_A, info_A, rois_B, pred_B, info_B,
        Bimg, N, C, best_s, best_b, sync_counter, out);
}